// Round 11
// baseline (96.282 us; speedup 1.0000x reference)
//
#include <hip/hip_runtime.h>

#define SN_NA    800
#define SN_F     128
#define SN_G     50
#define SN_MAXP  16384
#define SN_MAXN  128      // row slots: upper [0,64), lower [64,128)
#define SN_CUT2  25.0f

typedef __attribute__((ext_vector_type(4))) float f32x4;
typedef __attribute__((ext_vector_type(8))) short short8;

// ---- f32 bias offsets (elements, inside wb) ----
#define OB_BF1 0        // [3][128]
#define OB_BF2 384
#define OB_B2  768
#define OB_B3  1152
#define OB_BO1 1536     // [64]
#define OB_WO2 1600     // [64]
#define OB_BO2 1664     // [1]
#define NB_TOT 1665

// ---- bf16 transposed weights (elements, inside wtT): wT[col][k] = W[k][col] ----
#define OT_WF1T 0        // [3][128][64] (k>=50 zero)
#define OT_WF2T 24576    // [3][128][128]
#define OT_W2T  73728    // [3][128][128]
#define OT_W3T  122880   // [3][128][128]
#define OT_WINT 172032   // [3][128][128]
#define OT_WO1T 221184   // [64][128]
#define NT_TOT  229376

// ---- ws layout (bytes) ----
#define WO_PCNT  0
#define WO_DONE  32
#define WO_NCLO  64                       // 800*4 -> 3264   (memset 0..3264)
#define WO_NCUP  3264                     // -> 6464
#define WO_NBR   6464                     // 800*128*4 -> 416064 (packed p<<10|j)
#define WO_PAIRR 825664                   // 16384*4 -> 891200
#define WO_WB    891200                   // 1665*4 -> 897860
#define WO_WTT   897872                   // 229376*2 -> 1356624
#define WO_WPH   1356624                  // 3*16384*128*2 -> 13939536
#define WO_X     13939536                 // 800*128*4 -> 14349136
#define WO_XF    14349136                 // -> 14758736
#define WO_XF2   14758736                 // -> 15168336
#define WO_EPART 15168336                 // 512B (100 partials)
#define SN_WSNEED (WO_EPART + 512)

__device__ __forceinline__ float ldr(const void* p, int idx, int bf) {
    if (bf) {
        unsigned int x = ((unsigned int)(((const unsigned short*)p)[idx])) << 16;
        float f; __builtin_memcpy(&f, &x, 4); return f;
    }
    return ((const float*)p)[idx];
}
__device__ __forceinline__ int bfflag(const void* box) {
    float b0 = ((const float*)box)[0];    // f32: ~2.3 ; bf16 pair reinterpreted: denormal
    return !(b0 > 1e-3f && b0 < 1e3f);
}
__device__ __forceinline__ float bf2f(unsigned short u) {
    unsigned int x = ((unsigned int)u) << 16;
    float f; __builtin_memcpy(&f, &x, 4); return f;
}
__device__ __forceinline__ unsigned short f2bf(float v) {
    unsigned int b; __builtin_memcpy(&b, &v, 4);
    return (unsigned short)((b + 0x7FFFu + ((b >> 16) & 1u)) >> 16);
}
__device__ __forceinline__ float sspf(float v) {
    float sp = fmaxf(v, 0.0f) + log1pf(__expf(-fabsf(v)));
    return sp - 0.69314718055994530942f;
}

// ---------------- prep: setup (blocks 0..902) + pair/CSR build (903..1702) -----
__global__ void k_prep(const void* pos, const void* box,
                       const void* bf1w, const void* bf2w, const void* b2m, const void* b3m,
                       const void* bo1w, const void* wo2w, const void* bo2w,
                       const void* wf1, const void* wf2, const void* w2m, const void* w3m,
                       const void* winm, const void* wo1,
                       float* wb, unsigned short* wtT,
                       int* pcnt, int* ncup, int* nclo,
                       unsigned int* nbr, float* pairr) {
    __shared__ int   lj[64];
    __shared__ float lr[64];
    __shared__ int   lsh[2];
    int bf = bfflag(box);
    int bid = blockIdx.x, tid = threadIdx.x;

    if (bid < 7) {                      // biases -> f32
        int t = bid * 256 + tid;
        if (t < NB_TOT) {
            const int   sz[7] = {384,384,384,384,64,64,1};
            const void* ps[7] = {bf1w,bf2w,b2m,b3m,bo1w,wo2w,bo2w};
            int rem = t, s = 0;
#pragma unroll
            for (int q = 0; q < 7; q++) { if (rem >= sz[q]) { rem -= sz[q]; s = q+1; } else break; }
            wb[t] = ldr(ps[s], rem, bf);
        }
        return;
    }
    if (bid < 903) {                    // transposed bf16 weights
        int t = (bid - 7) * 256 + tid;
        if (t < NT_TOT) {
            float v;
            if (t < OT_WF2T) {
                int lay = t / 8192, rem = t - lay*8192, col = rem >> 6, k = rem & 63;
                v = (k < SN_G) ? ldr(wf1, lay*(SN_G*SN_F) + k*SN_F + col, bf) : 0.0f;
            } else if (t < OT_W2T) {
                int i2 = t - OT_WF2T; int lay = i2 >> 14, rem = i2 & 16383, col = rem >> 7, k = rem & 127;
                v = ldr(wf2, lay*16384 + k*128 + col, bf);
            } else if (t < OT_W3T) {
                int i2 = t - OT_W2T;  int lay = i2 >> 14, rem = i2 & 16383, col = rem >> 7, k = rem & 127;
                v = ldr(w2m, lay*16384 + k*128 + col, bf);
            } else if (t < OT_WINT) {
                int i2 = t - OT_W3T;  int lay = i2 >> 14, rem = i2 & 16383, col = rem >> 7, k = rem & 127;
                v = ldr(w3m, lay*16384 + k*128 + col, bf);
            } else if (t < OT_WO1T) {
                int i2 = t - OT_WINT; int lay = i2 >> 14, rem = i2 & 16383, col = rem >> 7, k = rem & 127;
                v = ldr(winm, lay*16384 + k*128 + col, bf);
            } else {
                int i2 = t - OT_WO1T; int col = i2 >> 7, k = i2 & 127;
                v = ldr(wo1, k*64 + col, bf);
            }
            wtT[t] = f2bf(v);
        }
        return;
    }

    // ---- build row i (block-aggregated pair reservation) ----
    int i = bid - 903;
    if (tid == 0) lsh[0] = 0;
    float c00 = ldr(box,0,bf)*10.f, c01 = ldr(box,1,bf)*10.f, c02 = ldr(box,2,bf)*10.f;
    float c10 = ldr(box,3,bf)*10.f, c11 = ldr(box,4,bf)*10.f, c12 = ldr(box,5,bf)*10.f;
    float c20 = ldr(box,6,bf)*10.f, c21 = ldr(box,7,bf)*10.f, c22 = ldr(box,8,bf)*10.f;
    float det = c00*(c11*c22 - c12*c21) - c01*(c10*c22 - c12*c20) + c02*(c10*c21 - c11*c20);
    float id  = 1.0f / det;
    float i00 = (c11*c22 - c12*c21)*id, i01 = (c02*c21 - c01*c22)*id, i02 = (c01*c12 - c02*c11)*id;
    float i10 = (c12*c20 - c10*c22)*id, i11 = (c00*c22 - c02*c20)*id, i12 = (c02*c10 - c00*c12)*id;
    float i20 = (c10*c21 - c11*c20)*id, i21 = (c01*c20 - c00*c21)*id, i22 = (c00*c11 - c01*c10)*id;
    float xi = ldr(pos, i*3+0, bf)*10.f;
    float yi = ldr(pos, i*3+1, bf)*10.f;
    float zi = ldr(pos, i*3+2, bf)*10.f;
    __syncthreads();

    for (int j = i + 1 + tid; j < SN_NA; j += 256) {
        float dx = xi - ldr(pos, j*3+0, bf)*10.f;
        float dy = yi - ldr(pos, j*3+1, bf)*10.f;
        float dz = zi - ldr(pos, j*3+2, bf)*10.f;
        float fx = dx*i00 + dy*i10 + dz*i20;
        float fy = dx*i01 + dy*i11 + dz*i21;
        float fz = dx*i02 + dy*i12 + dz*i22;
        fx -= rintf(fx); fy -= rintf(fy); fz -= rintf(fz);
        float ax = fx*c00 + fy*c10 + fz*c20;
        float ay = fx*c01 + fy*c11 + fz*c21;
        float az = fx*c02 + fy*c12 + fz*c22;
        float r2 = ax*ax + ay*ay + az*az;
        if (r2 < SN_CUT2) {
            int k = atomicAdd(&lsh[0], 1);
            if (k < 64) { lj[k] = j; lr[k] = sqrtf(r2); }
        }
    }
    __syncthreads();

    int cnt = lsh[0]; if (cnt > 64) cnt = 64;
    if (tid == 0) lsh[1] = atomicAdd(pcnt, cnt);
    __syncthreads();
    int base = lsh[1];
    int avail = SN_MAXP - base; if (avail < 0) avail = 0;
    int stored = cnt < avail ? cnt : avail;
    if (tid == 0) ncup[i] = stored;

    if (tid < stored) {
        int p = base + tid;
        int j = lj[tid];
        pairr[p] = lr[tid];
        nbr[i*SN_MAXN + tid] = ((unsigned int)p << 10) | (unsigned int)j;
        int kj = atomicAdd(&nclo[j], 1);
        if (kj < 64) nbr[j*SN_MAXN + 64 + kj] = ((unsigned int)p << 10) | (unsigned int)i;
    }
}

// ---------------- combined: init (blocks 0..49) + all-layer filter (50..3121) ----
// frags (m89-verified): A row=lane&15,k=(lane>>4)*8+e ; B col=lane&15 ; C col=lane&15,row=(lane>>4)*4+r
__global__ void k_initfilter(const int* zn, const void* emb, const void* box,
                             const float* pairr, const int* pcnt,
                             const float* wb, const unsigned short* wtT,
                             float* x, float* xf, unsigned short* wph) {
    __shared__ unsigned short es[16][136];
    __shared__ unsigned short gls[16][72];
    __shared__ unsigned short hls[16][136];
    int tid  = threadIdx.x;
    int lane = tid & 63;
    int wave = tid >> 6;
    int rowA = lane & 15;
    int kgrp = lane >> 4;

    if (blockIdx.x < 50) {
        // ---- init ----
        int bf = bfflag(box);
        int a0 = blockIdx.x * 16;
        int a = tid >> 4, f0 = (tid & 15) * 8;
        int atom = a0 + a;
        int z = zn[atom];
        float v[8];
#pragma unroll
        for (int q = 0; q < 8; q++) v[q] = ldr(emb, z*SN_F + f0 + q, bf);
        *(float4*)&x[atom*SN_F + f0]     = make_float4(v[0],v[1],v[2],v[3]);
        *(float4*)&x[atom*SN_F + f0 + 4] = make_float4(v[4],v[5],v[6],v[7]);
#pragma unroll
        for (int q = 0; q < 8; q++) es[a][f0+q] = f2bf(v[q]);
        __syncthreads();

        int c0 = wave * 32;
        f32x4 acc0 = {0.f,0.f,0.f,0.f}, acc1 = {0.f,0.f,0.f,0.f};
        const unsigned short* wn = wtT + OT_WINT;   // layer 0
#pragma unroll
        for (int ks = 0; ks < 4; ks++) {
            short8 a8 = *(const short8*)&es[rowA][ks*32 + kgrp*8];
            short8 w0 = *(const short8*)(wn + (c0 + rowA)*128      + ks*32 + kgrp*8);
            short8 w1 = *(const short8*)(wn + (c0 + 16 + rowA)*128 + ks*32 + kgrp*8);
            acc0 = __builtin_amdgcn_mfma_f32_16x16x32_bf16(a8, w0, acc0, 0, 0, 0);
            acc1 = __builtin_amdgcn_mfma_f32_16x16x32_bf16(a8, w1, acc1, 0, 0, 0);
        }
#pragma unroll
        for (int r = 0; r < 4; r++) {
            int row = kgrp*4 + r;
            xf[(a0 + row)*SN_F + c0 + rowA]      = acc0[r];
            xf[(a0 + row)*SN_F + c0 + 16 + rowA] = acc1[r];
        }
        return;
    }

    // ---- filter, all layers ----
    int fb  = blockIdx.x - 50;
    int lay = fb >> 10;
    int p0  = (fb & 1023) * 16;
    int cnt = *pcnt; if (cnt > SN_MAXP) cnt = SN_MAXP;
    if (p0 >= cnt) return;
    int c0 = wave * 32;

    {
        int pr = tid >> 4, k0 = (tid & 15) * 4;
        int p = p0 + pr;
        float r = (p < cnt) ? pairr[p] : -1.0f;
        const float width = 5.0f/49.0f, gamma = 0.5f/(width*width);
        unsigned short gv[4];
#pragma unroll
        for (int q = 0; q < 4; q++) {
            int k = k0 + q;
            float g = 0.f;
            if (k < SN_G && r >= 0.f) { float d = r - width*(float)k; g = __expf(-gamma*d*d); }
            gv[q] = f2bf(g);
        }
        *(unsigned long long*)&gls[pr][k0] = *(unsigned long long*)gv;
    }
    __syncthreads();

    f32x4 acc0 = {0.f,0.f,0.f,0.f}, acc1 = {0.f,0.f,0.f,0.f};
    const unsigned short* b1 = wtT + OT_WF1T + lay*8192;
#pragma unroll
    for (int ks = 0; ks < 2; ks++) {
        short8 a8 = *(const short8*)&gls[rowA][ks*32 + kgrp*8];
        short8 w0 = *(const short8*)(b1 + (c0 + rowA)*64      + ks*32 + kgrp*8);
        short8 w1 = *(const short8*)(b1 + (c0 + 16 + rowA)*64 + ks*32 + kgrp*8);
        acc0 = __builtin_amdgcn_mfma_f32_16x16x32_bf16(a8, w0, acc0, 0, 0, 0);
        acc1 = __builtin_amdgcn_mfma_f32_16x16x32_bf16(a8, w1, acc1, 0, 0, 0);
    }
    {
        float b1c0 = wb[OB_BF1 + lay*SN_F + c0 + rowA];
        float b1c1 = wb[OB_BF1 + lay*SN_F + c0 + 16 + rowA];
#pragma unroll
        for (int r = 0; r < 4; r++) {
            int row = kgrp*4 + r;
            hls[row][c0 + rowA]      = f2bf(sspf(acc0[r] + b1c0));
            hls[row][c0 + 16 + rowA] = f2bf(sspf(acc1[r] + b1c1));
        }
    }
    __syncthreads();

    f32x4 d0 = {0.f,0.f,0.f,0.f}, d1 = {0.f,0.f,0.f,0.f};
    const unsigned short* b2w = wtT + OT_WF2T + lay*16384;
#pragma unroll
    for (int ks = 0; ks < 4; ks++) {
        short8 a8 = *(const short8*)&hls[rowA][ks*32 + kgrp*8];
        short8 w0 = *(const short8*)(b2w + (c0 + rowA)*128      + ks*32 + kgrp*8);
        short8 w1 = *(const short8*)(b2w + (c0 + 16 + rowA)*128 + ks*32 + kgrp*8);
        d0 = __builtin_amdgcn_mfma_f32_16x16x32_bf16(a8, w0, d0, 0, 0, 0);
        d1 = __builtin_amdgcn_mfma_f32_16x16x32_bf16(a8, w1, d1, 0, 0, 0);
    }
    {
        unsigned short* wout = wph + lay*(SN_MAXP*SN_F);
        float b2c0 = wb[OB_BF2 + lay*SN_F + c0 + rowA];
        float b2c1 = wb[OB_BF2 + lay*SN_F + c0 + 16 + rowA];
#pragma unroll
        for (int r = 0; r < 4; r++) {
            int p = p0 + kgrp*4 + r;    // pad rows never referenced by CSR
            wout[p*SN_F + c0 + rowA]      = f2bf(d0[r] + b2c0);
            wout[p*SN_F + c0 + 16 + rowA] = f2bf(d1[r] + b2c1);
        }
    }
}

// ---------------- per-layer: gather + 3 MFMA GEMMs + residual (+ fused head) ----
// 100 blocks x 256 threads, 8 atoms/block (MFMA M=16 with 8 zero-pad rows).
__global__ void k_layerM(const int* ncup, const int* nclo,
                         const unsigned int* nbr,
                         const unsigned short* wph, const float* xf_in, float* x,
                         const float* wb, const unsigned short* wtT,
                         int lay, int layNext, float* xf_out,
                         float* epart, int* done, const void* box, void* out) {
    __shared__ unsigned int nl[8][128];
    __shared__ unsigned short ms[16][136], ts[16][136], xs[16][136];
    __shared__ float red[256];
    __shared__ int   lastf;
    int tid = threadIdx.x;
    int a0 = blockIdx.x * 8;
    int a = tid >> 5, l32 = tid & 31;
    int atom = a0 + a;
    int up = ncup[atom]; if (up > 64) up = 64;
    int lo = nclo[atom]; if (lo > 64) lo = 64;
    int cn = up + lo;
    for (int k = l32; k < up; k += 32) nl[a][k]      = nbr[atom*SN_MAXN + k];
    for (int k = l32; k < lo; k += 32) nl[a][up + k] = nbr[atom*SN_MAXN + 64 + k];
    // zero the 8 pad rows of ms (rows 8..15)
    ms[8 + (tid >> 5)][(tid & 31)*4 + 0] = 0;
    ms[8 + (tid >> 5)][(tid & 31)*4 + 1] = 0;
    ms[8 + (tid >> 5)][(tid & 31)*4 + 2] = 0;
    ms[8 + (tid >> 5)][(tid & 31)*4 + 3] = 0;
    __syncthreads();

    // gather m[a][f] = sum_k Wpk[f]*xf[jk][f]  (4 features/thread)
    {
        int f0 = l32 * 4;
        float acc[4] = {0.f,0.f,0.f,0.f};
        const unsigned short* wpb = wph + lay*(SN_MAXP*SN_F);
        int k = 0;
        for (; k + 2 <= cn; k += 2) {
            unsigned int v0 = nl[a][k], v1 = nl[a][k+1];
            ushort4 w0 = *(const ushort4*)(wpb + (v0 >> 10)*SN_F + f0);
            ushort4 w1 = *(const ushort4*)(wpb + (v1 >> 10)*SN_F + f0);
            float4  xa = *(const float4*)(xf_in + (v0 & 1023)*SN_F + f0);
            float4  xb = *(const float4*)(xf_in + (v1 & 1023)*SN_F + f0);
            acc[0] = fmaf(bf2f(w0.x), xa.x, fmaf(bf2f(w1.x), xb.x, acc[0]));
            acc[1] = fmaf(bf2f(w0.y), xa.y, fmaf(bf2f(w1.y), xb.y, acc[1]));
            acc[2] = fmaf(bf2f(w0.z), xa.z, fmaf(bf2f(w1.z), xb.z, acc[2]));
            acc[3] = fmaf(bf2f(w0.w), xa.w, fmaf(bf2f(w1.w), xb.w, acc[3]));
        }
        if (k < cn) {
            unsigned int v0 = nl[a][k];
            ushort4 w0 = *(const ushort4*)(wpb + (v0 >> 10)*SN_F + f0);
            float4  xa = *(const float4*)(xf_in + (v0 & 1023)*SN_F + f0);
            acc[0] = fmaf(bf2f(w0.x), xa.x, acc[0]);
            acc[1] = fmaf(bf2f(w0.y), xa.y, acc[1]);
            acc[2] = fmaf(bf2f(w0.z), xa.z, acc[2]);
            acc[3] = fmaf(bf2f(w0.w), xa.w, acc[3]);
        }
#pragma unroll
        for (int q = 0; q < 4; q++) ms[a][f0+q] = f2bf(acc[q]);
    }
    __syncthreads();

    int lane = tid & 63;
    int wave = tid >> 6;          // 4 waves, wave w owns cols [w*32, w*32+32)
    int c0   = wave * 32;
    int rowA = lane & 15;
    int kgrp = lane >> 4;

    // GEMM1: t = ssp(m @ W2 + b2)
    {
        f32x4 A0 = {0.f,0.f,0.f,0.f}, A1 = {0.f,0.f,0.f,0.f};
        const unsigned short* w = wtT + OT_W2T + lay*16384;
#pragma unroll
        for (int ks = 0; ks < 4; ks++) {
            short8 a8 = *(const short8*)&ms[rowA][ks*32 + kgrp*8];
            short8 w0 = *(const short8*)(w + (c0 + rowA)*128      + ks*32 + kgrp*8);
            short8 w1 = *(const short8*)(w + (c0 + 16 + rowA)*128 + ks*32 + kgrp*8);
            A0 = __builtin_amdgcn_mfma_f32_16x16x32_bf16(a8, w0, A0, 0, 0, 0);
            A1 = __builtin_amdgcn_mfma_f32_16x16x32_bf16(a8, w1, A1, 0, 0, 0);
        }
        float bc0 = wb[OB_B2 + lay*SN_F + c0 + rowA];
        float bc1 = wb[OB_B2 + lay*SN_F + c0 + 16 + rowA];
#pragma unroll
        for (int r = 0; r < 4; r++) {
            int row = kgrp*4 + r;
            ts[row][c0 + rowA]      = f2bf(sspf(A0[r] + bc0));
            ts[row][c0 + 16 + rowA] = f2bf(sspf(A1[r] + bc1));
        }
    }
    __syncthreads();

    // GEMM2: v = t @ W3 + b3 ; xnew = x + v (rows 0..7 only)
    {
        f32x4 A0 = {0.f,0.f,0.f,0.f}, A1 = {0.f,0.f,0.f,0.f};
        const unsigned short* w = wtT + OT_W3T + lay*16384;
#pragma unroll
        for (int ks = 0; ks < 4; ks++) {
            short8 a8 = *(const short8*)&ts[rowA][ks*32 + kgrp*8];
            short8 w0 = *(const short8*)(w + (c0 + rowA)*128      + ks*32 + kgrp*8);
            short8 w1 = *(const short8*)(w + (c0 + 16 + rowA)*128 + ks*32 + kgrp*8);
            A0 = __builtin_amdgcn_mfma_f32_16x16x32_bf16(a8, w0, A0, 0, 0, 0);
            A1 = __builtin_amdgcn_mfma_f32_16x16x32_bf16(a8, w1, A1, 0, 0, 0);
        }
        float bc0 = wb[OB_B3 + lay*SN_F + c0 + rowA];
        float bc1 = wb[OB_B3 + lay*SN_F + c0 + 16 + rowA];
#pragma unroll
        for (int r = 0; r < 4; r++) {
            int row = kgrp*4 + r;
            if (row < 8) {
                float xn0 = x[(a0 + row)*SN_F + c0 + rowA]      + A0[r] + bc0;
                float xn1 = x[(a0 + row)*SN_F + c0 + 16 + rowA] + A1[r] + bc1;
                x[(a0 + row)*SN_F + c0 + rowA]      = xn0;
                x[(a0 + row)*SN_F + c0 + 16 + rowA] = xn1;
                xs[row][c0 + rowA]      = f2bf(xn0);
                xs[row][c0 + 16 + rowA] = f2bf(xn1);
            } else {
                xs[row][c0 + rowA]      = 0;
                xs[row][c0 + 16 + rowA] = 0;
            }
        }
    }
    __syncthreads();

    if (layNext >= 0) {
        // GEMM3: xf_out = xnew @ Win[layNext] (rows 0..7 only)
        f32x4 A0 = {0.f,0.f,0.f,0.f}, A1 = {0.f,0.f,0.f,0.f};
        const unsigned short* w = wtT + OT_WINT + layNext*16384;
#pragma unroll
        for (int ks = 0; ks < 4; ks++) {
            short8 a8 = *(const short8*)&xs[rowA][ks*32 + kgrp*8];
            short8 w0 = *(const short8*)(w + (c0 + rowA)*128      + ks*32 + kgrp*8);
            short8 w1 = *(const short8*)(w + (c0 + 16 + rowA)*128 + ks*32 + kgrp*8);
            A0 = __builtin_amdgcn_mfma_f32_16x16x32_bf16(a8, w0, A0, 0, 0, 0);
            A1 = __builtin_amdgcn_mfma_f32_16x16x32_bf16(a8, w1, A1, 0, 0, 0);
        }
#pragma unroll
        for (int r = 0; r < 4; r++) {
            int row = kgrp*4 + r;
            if (row < 8) {
                xf_out[(a0 + row)*SN_F + c0 + rowA]      = A0[r];
                xf_out[(a0 + row)*SN_F + c0 + 16 + rowA] = A1[r];
            }
        }
        return;
    }

    // ---- layer 2: fused head over this block's 8-atom xs tile ----
    float e = 0.f;
    {
        int col = wave*16 + rowA;   // head cols 0..63 over 4 waves
        f32x4 H = {0.f,0.f,0.f,0.f};
        const unsigned short* w = wtT + OT_WO1T;
#pragma unroll
        for (int ks = 0; ks < 4; ks++) {
            short8 a8 = *(const short8*)&xs[rowA][ks*32 + kgrp*8];
            short8 w8 = *(const short8*)(w + col*128 + ks*32 + kgrp*8);
            H = __builtin_amdgcn_mfma_f32_16x16x32_bf16(a8, w8, H, 0, 0, 0);
        }
        if (kgrp < 2) {             // rows 0..7 only (pad rows excluded)
            float bo = wb[OB_BO1 + col];
            float wo = wb[OB_WO2 + col];
#pragma unroll
            for (int r = 0; r < 4; r++) e += sspf(H[r] + bo) * wo;
        }
    }
    red[tid] = e;
    __syncthreads();
    for (int wd = 128; wd > 0; wd >>= 1) {
        if (tid < wd) red[tid] += red[tid + wd];
        __syncthreads();
    }
    if (tid == 0) {
        epart[blockIdx.x] = red[0];
        __threadfence();                                  // release epart
        int old = atomicAdd(done, 1);                     // device-scope, one-shot
        lastf = (old == 99);
    }
    __syncthreads();
    if (lastf) {
        __threadfence();                                  // acquire others' epart
        red[tid] = (tid < 100) ? epart[tid] : 0.f;
        __syncthreads();
        for (int wd = 128; wd > 0; wd >>= 1) {
            if (tid < wd) red[tid] += red[tid + wd];
            __syncthreads();
        }
        if (tid == 0) {
            float v = red[0] + (float)SN_NA * wb[OB_BO2];
            if (bfflag(box)) ((unsigned short*)out)[0] = f2bf(v);
            else             ((float*)out)[0] = v;
        }
    }
}

__global__ void k_fail(void* out) {
    ((unsigned short*)out)[0] = 0x449A;   // bf16 1234.0 sentinel
}

extern "C" void kernel_launch(void* const* d_in, const int* in_sizes, int n_in,
                              void* d_out, int out_size, void* d_ws, size_t ws_size,
                              hipStream_t stream)
{
    const void* pos = d_in[0];
    const void* box = d_in[1];
    const int*  zn  = (const int*)d_in[2];
    const void* emb = d_in[3];

    if (ws_size < (size_t)SN_WSNEED) {
        k_fail<<<1, 1, 0, stream>>>(d_out);
        return;
    }

    char* ws = (char*)d_ws;
    int*            pcnt  = (int*)           (ws + WO_PCNT);
    int*            done  = (int*)           (ws + WO_DONE);
    int*            nclo  = (int*)           (ws + WO_NCLO);
    int*            ncup  = (int*)           (ws + WO_NCUP);
    unsigned int*   nbr   = (unsigned int*)  (ws + WO_NBR);
    float*          pairr = (float*)         (ws + WO_PAIRR);
    float*          wb    = (float*)         (ws + WO_WB);
    unsigned short* wtT   = (unsigned short*)(ws + WO_WTT);
    unsigned short* wph   = (unsigned short*)(ws + WO_WPH);
    float*          x     = (float*)         (ws + WO_X);
    float*          xfA   = (float*)         (ws + WO_XF);
    float*          xfB   = (float*)         (ws + WO_XF2);
    float*          epart = (float*)         (ws + WO_EPART);

    // zero pcnt, done, nclo (ws NOT re-poisoned between replays)
    hipMemsetAsync(ws, 0, 3264, stream);

    k_prep<<<1703, 256, 0, stream>>>(pos, box,
        d_in[5], d_in[7], d_in[10], d_in[12], d_in[14], d_in[15], d_in[16],
        d_in[4], d_in[6], d_in[9], d_in[11], d_in[8], d_in[13],
        wb, wtT, pcnt, ncup, nclo, nbr, pairr);

    k_initfilter<<<50 + 3*1024, 256, 0, stream>>>(zn, emb, box, pairr, pcnt,
                                                  wb, wtT, x, xfA, wph);

    float* xf_in = xfA;
    float* xf_out = xfB;
    for (int l = 0; l < 3; l++) {
        int layNext = (l < 2) ? (l + 1) : -1;
        k_layerM<<<100, 256, 0, stream>>>(ncup, nclo, nbr, wph, xf_in, x,
                                          wb, wtT, l, layNext, xf_out,
                                          epart, done, box, d_out);
        float* t = xf_in; xf_in = xf_out; xf_out = t;
    }
}